// Round 1
// baseline (224.604 us; speedup 1.0000x reference)
//
#include <hip/hip_runtime.h>

#define NB 16
#define NC 128
#define NH 8192
#define EPSN 1e-5f

// ---------------------------------------------------------------------------
// Transpose the two 128x128 conv weights so LDS staging reads are coalesced.
__global__ __launch_bounds__(256) void transpose_w_kernel(
    const float* __restrict__ w1, const float* __restrict__ w2,
    float* __restrict__ wt1, float* __restrict__ wt2) {
  int i = blockIdx.x * 256 + threadIdx.x;  // 16384 total
  int o = i >> 7;
  int c = i & 127;
  wt1[c * NC + o] = w1[o * NC + c];
  wt2[c * NC + o] = w2[o * NC + c];
}

// ---------------------------------------------------------------------------
// alpha[b,h] = sigmoid( sum_c Corr[b,c,h]*fcw[c] + sum_c Coh[b,c,h]*fcw[128+c] + fcb )
__global__ __launch_bounds__(256) void alpha_kernel(
    const float* __restrict__ corr, const float* __restrict__ coh,
    const float* __restrict__ fcw, const float* __restrict__ fcb,
    float* __restrict__ alpha) {
  int idx = blockIdx.x * 256 + threadIdx.x;  // B*H = 131072
  int b = idx >> 13;
  int h = idx & (NH - 1);
  const float* pc = corr + ((size_t)b * NC) * NH + h;
  const float* ph = coh + ((size_t)b * NC) * NH + h;
  float a0 = 0.f, a1 = 0.f, a2 = 0.f, a3 = 0.f;
#pragma unroll 8
  for (int c = 0; c < NC; c += 4) {
    a0 = fmaf(pc[(size_t)(c + 0) * NH], fcw[c + 0], a0);
    a1 = fmaf(pc[(size_t)(c + 1) * NH], fcw[c + 1], a1);
    a2 = fmaf(pc[(size_t)(c + 2) * NH], fcw[c + 2], a2);
    a3 = fmaf(pc[(size_t)(c + 3) * NH], fcw[c + 3], a3);
  }
#pragma unroll 8
  for (int c = 0; c < NC; c += 4) {
    a0 = fmaf(ph[(size_t)(c + 0) * NH], fcw[NC + c + 0], a0);
    a1 = fmaf(ph[(size_t)(c + 1) * NH], fcw[NC + c + 1], a1);
    a2 = fmaf(ph[(size_t)(c + 2) * NH], fcw[NC + c + 2], a2);
    a3 = fmaf(ph[(size_t)(c + 3) * NH], fcw[NC + c + 3], a3);
  }
  float l = (a0 + a1) + (a2 + a3) + fcb[0];
  alpha[idx] = 1.0f / (1.0f + __expf(-l));
}

// ---------------------------------------------------------------------------
// agg = corr - alpha*feats ; accumulate per-(b,c) sum / sumsq for InstanceNorm1.
__global__ __launch_bounds__(256) void agg_kernel(
    const float* __restrict__ corr, const float* __restrict__ feats,
    const float* __restrict__ alpha, float* __restrict__ agg,
    float* __restrict__ stats) {
  int blk = blockIdx.x;  // B*C*4 = 8192 blocks, 2048 elems each
  int chunk = blk & 3;
  int bc = blk >> 2;
  int b = bc >> 7;
  size_t base = (size_t)bc * NH + chunk * 2048;
  const float* pa = alpha + (size_t)b * NH + chunk * 2048;
  int t = threadIdx.x;
  float s = 0.f, q = 0.f;
#pragma unroll
  for (int r = 0; r < 2; ++r) {
    int off = r * 1024 + t * 4;
    float4 cv = *(const float4*)(corr + base + off);
    float4 fv = *(const float4*)(feats + base + off);
    float4 av = *(const float4*)(pa + off);
    float4 g;
    g.x = cv.x - av.x * fv.x;
    g.y = cv.y - av.y * fv.y;
    g.z = cv.z - av.z * fv.z;
    g.w = cv.w - av.w * fv.w;
    *(float4*)(agg + base + off) = g;
    s += (g.x + g.y) + (g.z + g.w);
    q = fmaf(g.x, g.x, q);
    q = fmaf(g.y, g.y, q);
    q = fmaf(g.z, g.z, q);
    q = fmaf(g.w, g.w, q);
  }
#pragma unroll
  for (int m = 32; m >= 1; m >>= 1) {
    s += __shfl_xor(s, m);
    q += __shfl_xor(q, m);
  }
  __shared__ float red[8];
  int wid = t >> 6;
  if ((t & 63) == 0) {
    red[wid * 2] = s;
    red[wid * 2 + 1] = q;
  }
  __syncthreads();
  if (t == 0) {
    float S = (red[0] + red[2]) + (red[4] + red[6]);
    float Q = (red[1] + red[3]) + (red[5] + red[7]);
    atomicAdd(&stats[bc * 2], S);
    atomicAdd(&stats[bc * 2 + 1], Q);
  }
}

// ---------------------------------------------------------------------------
// Fold IN (per b,c) + analytic BN (per c) + gamma/beta into per-(b,c) affine.
// BN mean is exactly 0 (input is IN output); BN var = mean_b[var_bc/(var_bc+eps)].
__global__ void finalize_kernel(const float* __restrict__ stats,
                                const float* __restrict__ g,
                                const float* __restrict__ be,
                                float* __restrict__ scale,
                                float* __restrict__ shift) {
  int c = threadIdx.x;  // 128 threads, 1 block
  float mean[NB], rstd[NB];
  float bnacc = 0.f;
#pragma unroll
  for (int b = 0; b < NB; ++b) {
    float s = stats[(b * NC + c) * 2];
    float q = stats[(b * NC + c) * 2 + 1];
    float m = s * (1.f / NH);
    float v = fmaxf(q * (1.f / NH) - m * m, 0.f);
    float r = rsqrtf(v + EPSN);
    mean[b] = m;
    rstd[b] = r;
    bnacc += v * r * r;  // = var/(var+eps) = E[y^2] after IN
  }
  float bnr = rsqrtf(bnacc * (1.f / NB) + EPSN);
  float gc = g[c], bec = be[c];
#pragma unroll
  for (int b = 0; b < NB; ++b) {
    float sc = rstd[b] * bnr * gc;
    scale[b * NC + c] = sc;
    shift[b * NC + c] = fmaf(-mean[b], sc, bec);
  }
}

// ---------------------------------------------------------------------------
// 1x1 conv with fused input affine+ReLU:
//   Out[b,o,h] = sum_c relu(X[b,c,h]*scale[b,c]+shift[b,c]) * Wt[c,o] + bias[o]
// Tile: 128 o x 128 h per workgroup, K chunked by 32. Optionally accumulates
// per-(b,o) sum/sumsq of the OUTPUT (for the next block's InstanceNorm).
// Safe when X == Out (all tile reads precede tile writes; tile is WG-exclusive).
__global__ __launch_bounds__(256) void conv_kernel(
    const float* X, const float* __restrict__ scale,
    const float* __restrict__ shift, const float* __restrict__ Wt,
    const float* __restrict__ bias, float* Out, float* __restrict__ stats) {
  __shared__ __align__(16) float sA[32][128];  // [c][h] 16 KB
  __shared__ __align__(16) float sW[32][132];  // [c][o] 16.5 KB (padded)
  const int b = blockIdx.x >> 6;         // 64 h-tiles per batch
  const int h0 = (blockIdx.x & 63) << 7; // tile of 128 h
  const int t = threadIdx.x;
  const int ho = (t & 15) * 8;   // 8 h per thread
  const int oo = (t >> 4) * 8;   // 8 o per thread

  float acc[8][8];
#pragma unroll
  for (int i = 0; i < 8; ++i)
#pragma unroll
    for (int j = 0; j < 8; ++j) acc[i][j] = 0.f;

  const int row = t >> 5;        // 0..7 (c rows per staging pass)
  const int col = (t & 31) * 4;  // 0..124

  for (int c0 = 0; c0 < NC; c0 += 32) {
#pragma unroll
    for (int r = 0; r < 4; ++r) {
      int c = c0 + row + r * 8;
      float sc = scale[b * NC + c];
      float sh = shift[b * NC + c];
      float4 v = *(const float4*)(X + ((size_t)(b * NC + c) << 13) + h0 + col);
      float4 u;
      u.x = fmaxf(fmaf(v.x, sc, sh), 0.f);
      u.y = fmaxf(fmaf(v.y, sc, sh), 0.f);
      u.z = fmaxf(fmaf(v.z, sc, sh), 0.f);
      u.w = fmaxf(fmaf(v.w, sc, sh), 0.f);
      *(float4*)&sA[row + r * 8][col] = u;
      *(float4*)&sW[row + r * 8][col] =
          *(const float4*)(Wt + ((size_t)(c0 + row + r * 8) << 7) + col);
    }
    __syncthreads();
#pragma unroll
    for (int cc = 0; cc < 32; ++cc) {
      float a[8], w[8];
      *(float4*)&a[0] = *(const float4*)&sA[cc][ho];
      *(float4*)&a[4] = *(const float4*)&sA[cc][ho + 4];
      *(float4*)&w[0] = *(const float4*)&sW[cc][oo];
      *(float4*)&w[4] = *(const float4*)&sW[cc][oo + 4];
#pragma unroll
      for (int i = 0; i < 8; ++i)
#pragma unroll
        for (int j = 0; j < 8; ++j) acc[i][j] = fmaf(w[i], a[j], acc[i][j]);
    }
    __syncthreads();
  }

  // Epilogue: add bias, write out, optional output stats.
#pragma unroll
  for (int i = 0; i < 8; ++i) {
    int o = oo + i;
    float bv = bias[o];
    float vals[8];
#pragma unroll
    for (int j = 0; j < 8; ++j) vals[j] = acc[i][j] + bv;
    float* po = Out + ((size_t)(b * NC + o) << 13) + h0 + ho;
    *(float4*)po = make_float4(vals[0], vals[1], vals[2], vals[3]);
    *(float4*)(po + 4) = make_float4(vals[4], vals[5], vals[6], vals[7]);
    if (stats) {
      float s = 0.f, q = 0.f;
#pragma unroll
      for (int j = 0; j < 8; ++j) {
        s += vals[j];
        q = fmaf(vals[j], vals[j], q);
      }
#pragma unroll
      for (int m = 1; m <= 8; m <<= 1) {
        s += __shfl_xor(s, m);
        q += __shfl_xor(q, m);
      }
      if ((t & 15) == 0) {
        atomicAdd(&stats[(b * NC + o) * 2], s);
        atomicAdd(&stats[(b * NC + o) * 2 + 1], q);
      }
    }
  }
}

// ---------------------------------------------------------------------------
extern "C" void kernel_launch(void* const* d_in, const int* in_sizes, int n_in,
                              void* d_out, int out_size, void* d_ws,
                              size_t ws_size, hipStream_t stream) {
  const float* corr = (const float*)d_in[0];
  const float* coh = (const float*)d_in[1];
  const float* feats = (const float*)d_in[2];
  const float* fcw = (const float*)d_in[3];
  const float* fcb = (const float*)d_in[4];
  const float* w1 = (const float*)d_in[5];
  const float* b1 = (const float*)d_in[6];
  const float* g1 = (const float*)d_in[7];
  const float* be1 = (const float*)d_in[8];
  const float* w2 = (const float*)d_in[9];
  const float* b2 = (const float*)d_in[10];
  const float* g2 = (const float*)d_in[11];
  const float* be2 = (const float*)d_in[12];

  float* out = (float*)d_out;  // holds agg -> x1 -> final output (in-place chain)
  float* ws = (float*)d_ws;
  float* alphab = ws;            // 131072
  float* wt1 = alphab + 131072;  // 16384
  float* wt2 = wt1 + 16384;      // 16384
  float* stats1 = wt2 + 16384;   // 4096
  float* stats2 = stats1 + 4096; // 4096
  float* scale1 = stats2 + 4096; // 2048
  float* shift1 = scale1 + 2048; // 2048
  float* scale2 = shift1 + 2048; // 2048
  float* shift2 = scale2 + 2048; // 2048

  hipMemsetAsync(stats1, 0, 8192 * sizeof(float), stream);  // stats1+stats2
  transpose_w_kernel<<<64, 256, 0, stream>>>(w1, w2, wt1, wt2);
  alpha_kernel<<<512, 256, 0, stream>>>(corr, coh, fcw, fcb, alphab);
  agg_kernel<<<8192, 256, 0, stream>>>(corr, feats, alphab, out, stats1);
  finalize_kernel<<<1, 128, 0, stream>>>(stats1, g1, be1, scale1, shift1);
  conv_kernel<<<1024, 256, 0, stream>>>(out, scale1, shift1, wt1, b1, out,
                                        stats2);
  finalize_kernel<<<1, 128, 0, stream>>>(stats2, g2, be2, scale2, shift2);
  conv_kernel<<<1024, 256, 0, stream>>>(out, scale2, shift2, wt2, b2, out,
                                        nullptr);
}

// Round 3
// 192.834 us; speedup vs baseline: 1.1647x; 1.1647x over previous
//
#include <hip/hip_runtime.h>

#define NB 16
#define NC 128
#define NH 8192
#define EPSN 1e-5f

typedef __attribute__((ext_vector_type(8))) short short8;
typedef __attribute__((ext_vector_type(4))) float f32x4;

__device__ inline unsigned short f2bf(float f) {
  unsigned int u = __builtin_bit_cast(unsigned int, f);
  u = u + 0x7FFFu + ((u >> 16) & 1u);
  return (unsigned short)(u >> 16);
}

// ---------------------------------------------------------------------------
// alpha[b,h] = sigmoid( sum_c Corr[b,c,h]*fcw[c] + sum_c Coh[b,c,h]*fcw[128+c] + fcb )
__global__ __launch_bounds__(256) void alpha_kernel(
    const float* __restrict__ corr, const float* __restrict__ coh,
    const float* __restrict__ fcw, const float* __restrict__ fcb,
    float* __restrict__ alpha) {
  int idx = blockIdx.x * 256 + threadIdx.x;  // B*H = 131072
  int b = idx >> 13;
  int h = idx & (NH - 1);
  const float* pc = corr + ((size_t)b * NC) * NH + h;
  const float* ph = coh + ((size_t)b * NC) * NH + h;
  float a0 = 0.f, a1 = 0.f, a2 = 0.f, a3 = 0.f;
#pragma unroll 8
  for (int c = 0; c < NC; c += 4) {
    a0 = fmaf(pc[(size_t)(c + 0) * NH], fcw[c + 0], a0);
    a1 = fmaf(pc[(size_t)(c + 1) * NH], fcw[c + 1], a1);
    a2 = fmaf(pc[(size_t)(c + 2) * NH], fcw[c + 2], a2);
    a3 = fmaf(pc[(size_t)(c + 3) * NH], fcw[c + 3], a3);
  }
#pragma unroll 8
  for (int c = 0; c < NC; c += 4) {
    a0 = fmaf(ph[(size_t)(c + 0) * NH], fcw[NC + c + 0], a0);
    a1 = fmaf(ph[(size_t)(c + 1) * NH], fcw[NC + c + 1], a1);
    a2 = fmaf(ph[(size_t)(c + 2) * NH], fcw[NC + c + 2], a2);
    a3 = fmaf(ph[(size_t)(c + 3) * NH], fcw[NC + c + 3], a3);
  }
  float l = (a0 + a1) + (a2 + a3) + fcb[0];
  alpha[idx] = 1.0f / (1.0f + __expf(-l));
}

// ---------------------------------------------------------------------------
// agg = corr - alpha*feats ; accumulate per-(b,c) sum / sumsq for InstanceNorm1.
__global__ __launch_bounds__(256) void agg_kernel(
    const float* __restrict__ corr, const float* __restrict__ feats,
    const float* __restrict__ alpha, float* __restrict__ agg,
    float* __restrict__ stats) {
  int blk = blockIdx.x;  // B*C*4 = 8192 blocks, 2048 elems each
  int chunk = blk & 3;
  int bc = blk >> 2;
  int b = bc >> 7;
  size_t base = (size_t)bc * NH + chunk * 2048;
  const float* pa = alpha + (size_t)b * NH + chunk * 2048;
  int t = threadIdx.x;
  float s = 0.f, q = 0.f;
#pragma unroll
  for (int r = 0; r < 2; ++r) {
    int off = r * 1024 + t * 4;
    float4 cv = *(const float4*)(corr + base + off);
    float4 fv = *(const float4*)(feats + base + off);
    float4 av = *(const float4*)(pa + off);
    float4 g;
    g.x = cv.x - av.x * fv.x;
    g.y = cv.y - av.y * fv.y;
    g.z = cv.z - av.z * fv.z;
    g.w = cv.w - av.w * fv.w;
    *(float4*)(agg + base + off) = g;
    s += (g.x + g.y) + (g.z + g.w);
    q = fmaf(g.x, g.x, q);
    q = fmaf(g.y, g.y, q);
    q = fmaf(g.z, g.z, q);
    q = fmaf(g.w, g.w, q);
  }
#pragma unroll
  for (int m = 32; m >= 1; m >>= 1) {
    s += __shfl_xor(s, m);
    q += __shfl_xor(q, m);
  }
  __shared__ float red[8];
  int wid = t >> 6;
  if ((t & 63) == 0) {
    red[wid * 2] = s;
    red[wid * 2 + 1] = q;
  }
  __syncthreads();
  if (t == 0) {
    float S = (red[0] + red[2]) + (red[4] + red[6]);
    float Q = (red[1] + red[3]) + (red[5] + red[7]);
    atomicAdd(&stats[bc * 2], S);
    atomicAdd(&stats[bc * 2 + 1], Q);
  }
}

// ---------------------------------------------------------------------------
// Fold IN (per b,c) + analytic BN (per c) + gamma/beta into per-(b,c) affine.
__global__ void finalize_kernel(const float* __restrict__ stats,
                                const float* __restrict__ g,
                                const float* __restrict__ be,
                                float* __restrict__ scale,
                                float* __restrict__ shift) {
  int c = threadIdx.x;  // 128 threads, 1 block
  float mean[NB], rstd[NB];
  float bnacc = 0.f;
#pragma unroll
  for (int b = 0; b < NB; ++b) {
    float s = stats[(b * NC + c) * 2];
    float q = stats[(b * NC + c) * 2 + 1];
    float m = s * (1.f / NH);
    float v = fmaxf(q * (1.f / NH) - m * m, 0.f);
    float r = rsqrtf(v + EPSN);
    mean[b] = m;
    rstd[b] = r;
    bnacc += v * r * r;
  }
  float bnr = rsqrtf(bnacc * (1.f / NB) + EPSN);
  float gc = g[c], bec = be[c];
#pragma unroll
  for (int b = 0; b < NB; ++b) {
    float sc = rstd[b] * bnr * gc;
    scale[b * NC + c] = sc;
    shift[b * NC + c] = fmaf(-mean[b], sc, bec);
  }
}

// ---------------------------------------------------------------------------
// bf16-MFMA 1x1 conv with fused input affine+ReLU.
//   Out[b,o,h] = sum_c relu(X[b,c,h]*scale[b,c]+shift[b,c]) * W[o,c] + bias[o]
// MFMA roles: A = W (M=o, K=c; register frags), B = Xn (K=c, N=h).
// Xn is staged into LDS DIRECTLY IN B-FRAGMENT ORDER:
//   halfword idx = fragid*512 + lane*8 + j, with
//   fragid = (h>>4)*4 + (c>>5), lane = 16*((c>>3)&3) + (h&15), j = c&7
// so each wave's B operand is one plain ds_read_b128 per (n-panel, k-step).
// Tile: 128o x 64h, K=128 staged once. In-place safe (reads precede writes
// within the block's exclusive h-tile). Optional per-(b,o) output stats.
__global__ __launch_bounds__(256) void conv_mfma_kernel(
    const float* X, const float* __restrict__ scale,
    const float* __restrict__ shift, const float* __restrict__ W,
    const float* __restrict__ bias, float* Out, float* __restrict__ stats) {
  __shared__ __align__(16) unsigned short sXf[8192];  // 16 frags x 512 halfwords
  __shared__ float ssum[NC], ssq[NC];
  const int t = threadIdx.x;
  const int b = blockIdx.x >> 7;
  const int h0 = (blockIdx.x & 127) << 6;  // 64-h tile
  const int lane = t & 63;
  const int wv = t >> 6;
  const int wo = wv >> 1;  // o-half: wo*64
  const int wh = wv & 1;   // h-half: wh*32

  const bool do_stats = (stats != nullptr);
  if (do_stats && t < NC) { ssum[t] = 0.f; ssq[t] = 0.f; }

  // ---- preload W frags (A operand): lane holds o = wo*64+m*16+(lane&15),
  //      c (=K) = k*32 + 8*(lane>>4) + j, j=0..7 contiguous
  short8 wfr[4][4];
  {
    const int orow = wo * 64 + (lane & 15);
    const int cb = 8 * (lane >> 4);
#pragma unroll
    for (int m = 0; m < 4; ++m) {
#pragma unroll
      for (int k = 0; k < 4; ++k) {
        const float* p = W + (orow + m * 16) * NC + k * 32 + cb;
        float4 lo = *(const float4*)p;
        float4 hi = *(const float4*)(p + 4);
        union { short8 s; unsigned short u[8]; } fr;
        fr.u[0] = f2bf(lo.x); fr.u[1] = f2bf(lo.y);
        fr.u[2] = f2bf(lo.z); fr.u[3] = f2bf(lo.w);
        fr.u[4] = f2bf(hi.x); fr.u[5] = f2bf(hi.y);
        fr.u[6] = f2bf(hi.z); fr.u[7] = f2bf(hi.w);
        wfr[m][k] = fr.s;
      }
    }
  }

  // ---- stage X (128c x 64h): f32 float4 load -> affine+relu -> bf16
  //      -> scatter into B-fragment order (4 scalar b16 writes, 16B stride)
  {
    const int q = t >> 4;   // c = p*16 + q
    const int hq = t & 15;  // h = 4*hq + r
#pragma unroll
    for (int p = 0; p < 8; ++p) {
      int c = p * 16 + q;
      float sc = scale[b * NC + c];
      float sh = shift[b * NC + c];
      float4 v = *(const float4*)(X + ((size_t)(b * NC + c) << 13) + h0 + hq * 4);
      // fragid = (hq>>2)*4 + (c>>5); lane = 16*((c>>3)&3) + (hq&3)*4 + r; j = c&7
      int base = (((hq >> 2) * 4 + (c >> 5)) << 9) +
                 ((16 * ((c >> 3) & 3) + (hq & 3) * 4) << 3) + (c & 7);
      sXf[base]      = f2bf(fmaxf(fmaf(v.x, sc, sh), 0.f));
      sXf[base + 8]  = f2bf(fmaxf(fmaf(v.y, sc, sh), 0.f));
      sXf[base + 16] = f2bf(fmaxf(fmaf(v.z, sc, sh), 0.f));
      sXf[base + 24] = f2bf(fmaxf(fmaf(v.w, sc, sh), 0.f));
    }
  }
  __syncthreads();

  // ---- MFMA main loop: 8 ds_read_b128 per wave, 32 MFMAs
  f32x4 acc[4][2];
#pragma unroll
  for (int m = 0; m < 4; ++m) {
    acc[m][0] = (f32x4){0.f, 0.f, 0.f, 0.f};
    acc[m][1] = (f32x4){0.f, 0.f, 0.f, 0.f};
  }
#pragma unroll
  for (int k = 0; k < 4; ++k) {
    short8 x0 = *(const short8*)&sXf[(((wh * 2 + 0) * 4 + k) << 9) + lane * 8];
    short8 x1 = *(const short8*)&sXf[(((wh * 2 + 1) * 4 + k) << 9) + lane * 8];
#pragma unroll
    for (int m = 0; m < 4; ++m) {
      acc[m][0] = __builtin_amdgcn_mfma_f32_16x16x32_bf16(wfr[m][k], x0, acc[m][0], 0, 0, 0);
      acc[m][1] = __builtin_amdgcn_mfma_f32_16x16x32_bf16(wfr[m][k], x1, acc[m][1], 0, 0, 0);
    }
  }

  // ---- epilogue: bias, store f32 [o][h], optional output stats
  const int og = 4 * (lane >> 4);
  const int hcol = lane & 15;
  const int ha = h0 + wh * 32 + hcol;
#pragma unroll
  for (int m = 0; m < 4; ++m) {
    int obase = wo * 64 + m * 16 + og;
#pragma unroll
    for (int r = 0; r < 4; ++r) {
      int o = obase + r;
      float bv = bias[o];
      float v0 = acc[m][0][r] + bv;
      float v1 = acc[m][1][r] + bv;
      float* po = Out + ((size_t)(b * NC + o) << 13);
      po[ha] = v0;
      po[ha + 16] = v1;
      if (do_stats) {
        float s2 = v0 + v1;
        float q2 = fmaf(v0, v0, v1 * v1);
#pragma unroll
        for (int mm = 1; mm <= 8; mm <<= 1) {
          s2 += __shfl_xor(s2, mm);
          q2 += __shfl_xor(q2, mm);
        }
        if (hcol == 0) {
          atomicAdd(&ssum[o], s2);
          atomicAdd(&ssq[o], q2);
        }
      }
    }
  }
  if (do_stats) {
    __syncthreads();
    if (t < NC) {
      atomicAdd(&stats[(b * NC + t) * 2], ssum[t]);
      atomicAdd(&stats[(b * NC + t) * 2 + 1], ssq[t]);
    }
  }
}

// ---------------------------------------------------------------------------
extern "C" void kernel_launch(void* const* d_in, const int* in_sizes, int n_in,
                              void* d_out, int out_size, void* d_ws,
                              size_t ws_size, hipStream_t stream) {
  const float* corr = (const float*)d_in[0];
  const float* coh = (const float*)d_in[1];
  const float* feats = (const float*)d_in[2];
  const float* fcw = (const float*)d_in[3];
  const float* fcb = (const float*)d_in[4];
  const float* w1 = (const float*)d_in[5];
  const float* b1 = (const float*)d_in[6];
  const float* g1 = (const float*)d_in[7];
  const float* be1 = (const float*)d_in[8];
  const float* w2 = (const float*)d_in[9];
  const float* b2 = (const float*)d_in[10];
  const float* g2 = (const float*)d_in[11];
  const float* be2 = (const float*)d_in[12];

  float* out = (float*)d_out;  // agg -> x1 -> final output (in-place chain)
  float* ws = (float*)d_ws;
  float* alphab = ws;               // 131072
  float* stats1 = alphab + 131072;  // 4096
  float* stats2 = stats1 + 4096;    // 4096
  float* scale1 = stats2 + 4096;    // 2048
  float* shift1 = scale1 + 2048;    // 2048
  float* scale2 = shift1 + 2048;    // 2048
  float* shift2 = scale2 + 2048;    // 2048

  hipMemsetAsync(stats1, 0, 8192 * sizeof(float), stream);  // stats1+stats2
  alpha_kernel<<<512, 256, 0, stream>>>(corr, coh, fcw, fcb, alphab);
  agg_kernel<<<8192, 256, 0, stream>>>(corr, feats, alphab, out, stats1);
  finalize_kernel<<<1, 128, 0, stream>>>(stats1, g1, be1, scale1, shift1);
  conv_mfma_kernel<<<2048, 256, 0, stream>>>(out, scale1, shift1, w1, b1, out,
                                             stats2);
  finalize_kernel<<<1, 128, 0, stream>>>(stats2, g2, be2, scale2, shift2);
  conv_mfma_kernel<<<2048, 256, 0, stream>>>(out, scale2, shift2, w2, b2, out,
                                             nullptr);
}

// Round 4
// 132.769 us; speedup vs baseline: 1.6917x; 1.4524x over previous
//
#include <hip/hip_runtime.h>

#define NB 16
#define NC 128
#define NH 8192
#define EPSN 1e-5f

typedef __attribute__((ext_vector_type(8))) short short8;
typedef __attribute__((ext_vector_type(4))) float f32x4;

__device__ inline unsigned short f2bf(float f) {
  unsigned int u = __builtin_bit_cast(unsigned int, f);
  u = u + 0x7FFFu + ((u >> 16) & 1u);
  return (unsigned short)(u >> 16);
}

// ---------------------------------------------------------------------------
// alpha[b,h] = sigmoid( sum_c Corr[b,c,h]*fcw[c] + sum_c Coh[b,c,h]*fcw[128+c] + fcb )
__global__ __launch_bounds__(256) void alpha_kernel(
    const float* __restrict__ corr, const float* __restrict__ coh,
    const float* __restrict__ fcw, const float* __restrict__ fcb,
    float* __restrict__ alpha) {
  int idx = blockIdx.x * 256 + threadIdx.x;  // B*H = 131072
  int b = idx >> 13;
  int h = idx & (NH - 1);
  const float* pc = corr + ((size_t)b * NC) * NH + h;
  const float* ph = coh + ((size_t)b * NC) * NH + h;
  float a0 = 0.f, a1 = 0.f, a2 = 0.f, a3 = 0.f;
#pragma unroll 8
  for (int c = 0; c < NC; c += 4) {
    a0 = fmaf(pc[(size_t)(c + 0) * NH], fcw[c + 0], a0);
    a1 = fmaf(pc[(size_t)(c + 1) * NH], fcw[c + 1], a1);
    a2 = fmaf(pc[(size_t)(c + 2) * NH], fcw[c + 2], a2);
    a3 = fmaf(pc[(size_t)(c + 3) * NH], fcw[c + 3], a3);
  }
#pragma unroll 8
  for (int c = 0; c < NC; c += 4) {
    a0 = fmaf(ph[(size_t)(c + 0) * NH], fcw[NC + c + 0], a0);
    a1 = fmaf(ph[(size_t)(c + 1) * NH], fcw[NC + c + 1], a1);
    a2 = fmaf(ph[(size_t)(c + 2) * NH], fcw[NC + c + 2], a2);
    a3 = fmaf(ph[(size_t)(c + 3) * NH], fcw[NC + c + 3], a3);
  }
  float l = (a0 + a1) + (a2 + a3) + fcb[0];
  alpha[idx] = 1.0f / (1.0f + __expf(-l));
}

// ---------------------------------------------------------------------------
// agg = corr - alpha*feats ; accumulate per-(b,c) sum / sumsq for InstanceNorm1.
__global__ __launch_bounds__(256) void agg_kernel(
    const float* __restrict__ corr, const float* __restrict__ feats,
    const float* __restrict__ alpha, float* __restrict__ agg,
    float* __restrict__ stats) {
  int blk = blockIdx.x;  // B*C*4 = 8192 blocks, 2048 elems each
  int chunk = blk & 3;
  int bc = blk >> 2;
  int b = bc >> 7;
  size_t base = (size_t)bc * NH + chunk * 2048;
  const float* pa = alpha + (size_t)b * NH + chunk * 2048;
  int t = threadIdx.x;
  float s = 0.f, q = 0.f;
#pragma unroll
  for (int r = 0; r < 2; ++r) {
    int off = r * 1024 + t * 4;
    float4 cv = *(const float4*)(corr + base + off);
    float4 fv = *(const float4*)(feats + base + off);
    float4 av = *(const float4*)(pa + off);
    float4 g;
    g.x = cv.x - av.x * fv.x;
    g.y = cv.y - av.y * fv.y;
    g.z = cv.z - av.z * fv.z;
    g.w = cv.w - av.w * fv.w;
    *(float4*)(agg + base + off) = g;
    s += (g.x + g.y) + (g.z + g.w);
    q = fmaf(g.x, g.x, q);
    q = fmaf(g.y, g.y, q);
    q = fmaf(g.z, g.z, q);
    q = fmaf(g.w, g.w, q);
  }
#pragma unroll
  for (int m = 32; m >= 1; m >>= 1) {
    s += __shfl_xor(s, m);
    q += __shfl_xor(q, m);
  }
  __shared__ float red[8];
  int wid = t >> 6;
  if ((t & 63) == 0) {
    red[wid * 2] = s;
    red[wid * 2 + 1] = q;
  }
  __syncthreads();
  if (t == 0) {
    float S = (red[0] + red[2]) + (red[4] + red[6]);
    float Q = (red[1] + red[3]) + (red[5] + red[7]);
    atomicAdd(&stats[bc * 2], S);
    atomicAdd(&stats[bc * 2 + 1], Q);
  }
}

// ---------------------------------------------------------------------------
// Fold IN (per b,c) + analytic BN (per c) + gamma/beta into per-(b,c) affine.
__global__ void finalize_kernel(const float* __restrict__ stats,
                                const float* __restrict__ g,
                                const float* __restrict__ be,
                                float* __restrict__ scale,
                                float* __restrict__ shift) {
  int c = threadIdx.x;  // 128 threads, 1 block
  float mean[NB], rstd[NB];
  float bnacc = 0.f;
#pragma unroll
  for (int b = 0; b < NB; ++b) {
    float s = stats[(b * NC + c) * 2];
    float q = stats[(b * NC + c) * 2 + 1];
    float m = s * (1.f / NH);
    float v = fmaxf(q * (1.f / NH) - m * m, 0.f);
    float r = rsqrtf(v + EPSN);
    mean[b] = m;
    rstd[b] = r;
    bnacc += v * r * r;
  }
  float bnr = rsqrtf(bnacc * (1.f / NB) + EPSN);
  float gc = g[c], bec = be[c];
#pragma unroll
  for (int b = 0; b < NB; ++b) {
    float sc = rstd[b] * bnr * gc;
    scale[b * NC + c] = sc;
    shift[b * NC + c] = fmaf(-mean[b], sc, bec);
  }
}

// ---------------------------------------------------------------------------
// bf16-MFMA 1x1 conv with fused input affine+ReLU, tile-looped + pipelined.
//   Out[b,o,h] = sum_c relu(X[b,c,h]*scale[b,c]+shift[b,c]) * W[o,c] + bias[o]
// Pre-swizzle LDS layout identical to round 3 (B-fragment order):
//   halfword idx = fragid*512 + sublane*8 + j
//   fragid = (h>>4)*4 + (c>>5), sublane = 16*((c>>3)&3) + (h&15), j = c&7
// XOR swizzle byte ^= ((byte>>7)&7)<<4 applied to BOTH ds_write and ds_read
// (bijective involution; makes b128 writes <=2-way and reads conflict-free).
// Each block: one b, 4 consecutive 64-h tiles; prefetch of tile t+1 issued
// BEFORE the mid-iteration barrier => in-place X==Out is race-free (every
// thread's loads are vmcnt-retired before any thread's post-barrier stores).
template <bool DOSTATS>
__global__ __launch_bounds__(256) void conv_mfma_kernel(
    const float* X, const float* __restrict__ scale,
    const float* __restrict__ shift, const float* __restrict__ W,
    const float* __restrict__ bias, float* Out, float* __restrict__ stats) {
  __shared__ __align__(16) unsigned short sXf[8192];  // 16 frags x 1 KB
  __shared__ float ssum[NC], ssq[NC];
  const int t = threadIdx.x;
  const int b = blockIdx.x >> 5;             // 32 blocks per batch
  const int hbase = (blockIdx.x & 31) << 8;  // 256 h per block (4 tiles)
  const int lane = t & 63;
  const int wv = t >> 6;
  const int wo = wv >> 1;  // o-half: wo*64
  const int wh = wv & 1;   // h-half within tile: wh*32

  if (DOSTATS && t < NC) { ssum[t] = 0.f; ssq[t] = 0.f; }

  // staging ownership: 8 consecutive c x 4 consecutive h per thread
  const int cb = (t >> 4) << 3;  // 0,8,...,120
  const int hq = t & 15;         // local h = hq*4 + r
  const int fragw = ((hq >> 2) << 2) + (cb >> 5);
  const int sub0 = (((cb >> 3) & 3) << 4) + ((hq & 3) << 2);
  const unsigned swz = ((unsigned)(sub0 >> 3)) << 4;  // r-invariant (sub0%8 + r <= 7)
  // read addr: frag*1024 + swizzled(lane*16)
  const unsigned br = ((unsigned)(lane << 4)) ^ (((unsigned)(lane >> 3)) << 4);

  const float* Xb = X + ((size_t)(b * NC) << 13);
  float* Ob = Out + ((size_t)(b * NC) << 13);

  // ---- prologue: issue tile-0 loads first (critical path)
  float4 xv[8];
#pragma unroll
  for (int p = 0; p < 8; ++p)
    xv[p] = *(const float4*)(Xb + ((size_t)(cb + p) << 13) + hbase + hq * 4);

  float scv[8], shv[8];
#pragma unroll
  for (int p = 0; p < 8; ++p) {
    scv[p] = scale[b * NC + cb + p];
    shv[p] = shift[b * NC + cb + p];
  }

  // ---- W frags (A operand), loaded once per block:
  //      lane holds o = wo*64+m*16+(lane&15), c = k*32 + 8*(lane>>4) + j
  short8 wfr[4][4];
  {
    const int orow = wo * 64 + (lane & 15);
    const int cbw = 8 * (lane >> 4);
#pragma unroll
    for (int m = 0; m < 4; ++m) {
#pragma unroll
      for (int k = 0; k < 4; ++k) {
        const float* p = W + (orow + m * 16) * NC + k * 32 + cbw;
        float4 lo = *(const float4*)p;
        float4 hi = *(const float4*)(p + 4);
        union { short8 s; unsigned short u[8]; } fr;
        fr.u[0] = f2bf(lo.x); fr.u[1] = f2bf(lo.y);
        fr.u[2] = f2bf(lo.z); fr.u[3] = f2bf(lo.w);
        fr.u[4] = f2bf(hi.x); fr.u[5] = f2bf(hi.y);
        fr.u[6] = f2bf(hi.z); fr.u[7] = f2bf(hi.w);
        wfr[m][k] = fr.s;
      }
    }
  }

  float as_[4][4], aq_[4][4];
  if (DOSTATS) {
#pragma unroll
    for (int m = 0; m < 4; ++m)
#pragma unroll
      for (int r = 0; r < 4; ++r) { as_[m][r] = 0.f; aq_[m][r] = 0.f; }
  }

  const int og = (lane >> 4) << 2;
  const int hcol = lane & 15;

  for (int tt = 0; tt < 4; ++tt) {
    // ---- convert + pack + 4x ds_write_b128 (swizzled)
#pragma unroll
    for (int r = 0; r < 4; ++r) {
      union { short8 s; unsigned short u[8]; } pk;
#pragma unroll
      for (int p = 0; p < 8; ++p) {
        float v = (r == 0) ? xv[p].x : (r == 1) ? xv[p].y : (r == 2) ? xv[p].z : xv[p].w;
        pk.u[p] = f2bf(fmaxf(fmaf(v, scv[p], shv[p]), 0.f));
      }
      unsigned addr = ((unsigned)(fragw << 10)) + ((((unsigned)(sub0 + r)) << 4) ^ swz);
      *(short8*)((char*)sXf + addr) = pk.s;
    }
    // ---- prefetch tile t+1 (MUST precede the barrier: in-place safety)
    if (tt < 3) {
#pragma unroll
      for (int p = 0; p < 8; ++p)
        xv[p] = *(const float4*)(Xb + ((size_t)(cb + p) << 13) + hbase +
                                 (tt + 1) * 64 + hq * 4);
    }
    __syncthreads();

    // ---- MFMA: 8 ds_read_b128 + 32 MFMAs per wave
    f32x4 acc[4][2];
#pragma unroll
    for (int m = 0; m < 4; ++m) {
      acc[m][0] = (f32x4){0.f, 0.f, 0.f, 0.f};
      acc[m][1] = (f32x4){0.f, 0.f, 0.f, 0.f};
    }
#pragma unroll
    for (int k = 0; k < 4; ++k) {
      short8 x0 = *(const short8*)((char*)sXf + (((wh * 2 + 0) * 4 + k) << 10) + br);
      short8 x1 = *(const short8*)((char*)sXf + (((wh * 2 + 1) * 4 + k) << 10) + br);
#pragma unroll
      for (int m = 0; m < 4; ++m) {
        acc[m][0] = __builtin_amdgcn_mfma_f32_16x16x32_bf16(wfr[m][k], x0, acc[m][0], 0, 0, 0);
        acc[m][1] = __builtin_amdgcn_mfma_f32_16x16x32_bf16(wfr[m][k], x1, acc[m][1], 0, 0, 0);
      }
    }

    // ---- epilogue: bias, store f32 [o][h], register stats accumulation
    const int ha = hbase + tt * 64 + wh * 32 + hcol;
#pragma unroll
    for (int m = 0; m < 4; ++m) {
      int obase = wo * 64 + m * 16 + og;
#pragma unroll
      for (int r = 0; r < 4; ++r) {
        int o = obase + r;
        float bv = bias[o];
        float v0 = acc[m][0][r] + bv;
        float v1 = acc[m][1][r] + bv;
        float* po = Ob + ((size_t)o << 13);
        po[ha] = v0;
        po[ha + 16] = v1;
        if (DOSTATS) {
          as_[m][r] += v0 + v1;
          aq_[m][r] = fmaf(v0, v0, fmaf(v1, v1, aq_[m][r]));
        }
      }
    }
    __syncthreads();  // guard LDS reuse by next iteration's ds_write
  }

  if (DOSTATS) {
#pragma unroll
    for (int m = 0; m < 4; ++m) {
#pragma unroll
      for (int r = 0; r < 4; ++r) {
        float s = as_[m][r], q = aq_[m][r];
#pragma unroll
        for (int mm = 1; mm <= 8; mm <<= 1) {
          s += __shfl_xor(s, mm);
          q += __shfl_xor(q, mm);
        }
        if (hcol == 0) {
          int o = wo * 64 + m * 16 + og + r;
          atomicAdd(&ssum[o], s);
          atomicAdd(&ssq[o], q);
        }
      }
    }
    __syncthreads();
    if (t < NC) {
      atomicAdd(&stats[(b * NC + t) * 2], ssum[t]);
      atomicAdd(&stats[(b * NC + t) * 2 + 1], ssq[t]);
    }
  }
}

// ---------------------------------------------------------------------------
extern "C" void kernel_launch(void* const* d_in, const int* in_sizes, int n_in,
                              void* d_out, int out_size, void* d_ws,
                              size_t ws_size, hipStream_t stream) {
  const float* corr = (const float*)d_in[0];
  const float* coh = (const float*)d_in[1];
  const float* feats = (const float*)d_in[2];
  const float* fcw = (const float*)d_in[3];
  const float* fcb = (const float*)d_in[4];
  const float* w1 = (const float*)d_in[5];
  const float* b1 = (const float*)d_in[6];
  const float* g1 = (const float*)d_in[7];
  const float* be1 = (const float*)d_in[8];
  const float* w2 = (const float*)d_in[9];
  const float* b2 = (const float*)d_in[10];
  const float* g2 = (const float*)d_in[11];
  const float* be2 = (const float*)d_in[12];

  float* out = (float*)d_out;  // agg -> x1 -> final output (in-place chain)
  float* ws = (float*)d_ws;
  float* alphab = ws;               // 131072
  float* stats1 = alphab + 131072;  // 4096
  float* stats2 = stats1 + 4096;    // 4096
  float* scale1 = stats2 + 4096;    // 2048
  float* shift1 = scale1 + 2048;    // 2048
  float* scale2 = shift1 + 2048;    // 2048
  float* shift2 = scale2 + 2048;    // 2048

  hipMemsetAsync(stats1, 0, 8192 * sizeof(float), stream);  // stats1+stats2
  alpha_kernel<<<512, 256, 0, stream>>>(corr, coh, fcw, fcb, alphab);
  agg_kernel<<<8192, 256, 0, stream>>>(corr, feats, alphab, out, stats1);
  finalize_kernel<<<1, 128, 0, stream>>>(stats1, g1, be1, scale1, shift1);
  conv_mfma_kernel<true><<<512, 256, 0, stream>>>(out, scale1, shift1, w1, b1,
                                                  out, stats2);
  finalize_kernel<<<1, 128, 0, stream>>>(stats2, g2, be2, scale2, shift2);
  conv_mfma_kernel<false><<<512, 256, 0, stream>>>(out, scale2, shift2, w2, b2,
                                                   out, nullptr);
}